// Round 1
// baseline (5528.341 us; speedup 1.0000x reference)
//
#include <hip/hip_runtime.h>

#define DIM 256
#define NLr 16384
#define NGr 32768
#define NDr 8192
#define NE  262144

typedef short bf16x8 __attribute__((ext_vector_type(8)));
typedef float f32x4 __attribute__((ext_vector_type(4)));

__device__ __forceinline__ unsigned short f2bf(float f) {
  unsigned int u = __builtin_bit_cast(unsigned int, f);
  u += 0x7fffu + ((u >> 16) & 1u);
  return (unsigned short)(u >> 16);
}
__device__ __forceinline__ float bf2f(unsigned short b) {
  return __builtin_bit_cast(float, ((unsigned int)b) << 16);
}

struct WPtrs { const float* p[9]; };

// ---- convert 9 weight matrices (f32 -> bf16), 65536 elems each ----
__global__ __launch_bounds__(256) void conv_w_kernel(WPtrs wp, unsigned short* __restrict__ dst) {
  int m = blockIdx.y;
  int i = blockIdx.x * 256 + threadIdx.x;
  dst[m * 65536 + i] = f2bf(wp.p[m][i]);
}

// ---- scatter: acc[dst] += w * h_src[src]; deg[dst] += w.  One wave per edge. ----
__global__ __launch_bounds__(256) void scatter_kernel(
    const float* __restrict__ hsrc, const int* __restrict__ src,
    const int* __restrict__ dst, const float* __restrict__ w,
    float* __restrict__ acc, float* __restrict__ deg) {
  int t = blockIdx.x * 256 + threadIdx.x;
  int e = t >> 6, lane = t & 63;
  int s = src[e], d = dst[e];
  float wv = w[e];
  float4 x = reinterpret_cast<const float4*>(hsrc)[s * 64 + lane];
  float* dp = acc + (size_t)d * DIM + lane * 4;
  unsafeAtomicAdd(dp + 0, x.x * wv);
  unsafeAtomicAdd(dp + 1, x.y * wv);
  unsafeAtomicAdd(dp + 2, x.z * wv);
  unsafeAtomicAdd(dp + 3, x.w * wv);
  if (lane == 0) unsafeAtomicAdd(deg + d, wv);
}

// ---- shared GEMM pieces: 64 rows x (256x256) bf16 MFMA ----
__device__ __forceinline__ void stage_x(const float* __restrict__ g, int r0,
                                        unsigned short* xs, int tid) {
#pragma unroll
  for (int it = 0; it < 16; ++it) {
    int i = it * 256 + tid;
    int row = i >> 6, q = i & 63;
    float4 v = reinterpret_cast<const float4*>(g)[(size_t)(r0 + row) * 64 + q];
    ushort4 b;
    b.x = f2bf(v.x); b.y = f2bf(v.y); b.z = f2bf(v.z); b.w = f2bf(v.w);
    *reinterpret_cast<ushort4*>(&xs[row * 264 + q * 4]) = b;
  }
}

__device__ __forceinline__ void gemm_frag(const unsigned short* xs,
                                          const unsigned short* __restrict__ Wg,
                                          unsigned short* wl, int tid,
                                          f32x4 accv[4][4]) {
  const int wid = tid >> 6, lhi = (tid & 63) >> 4, llo = tid & 15;
  for (int ks = 0; ks < 8; ++ks) {
    const int k0 = ks * 32;
    __syncthreads();  // protects xs (first iter) and wl reads from prev iter
    {
      const uint4* gp = reinterpret_cast<const uint4*>(Wg + (size_t)tid * 256 + k0);
      uint4 a0 = gp[0], a1 = gp[1], a2 = gp[2], a3 = gp[3];
      uint4* lp = reinterpret_cast<uint4*>(wl + tid * 56);
      lp[0] = a0; lp[1] = a1; lp[2] = a2; lp[3] = a3;
    }
    __syncthreads();
    bf16x8 afr[4], bfr[4];
#pragma unroll
    for (int rt = 0; rt < 4; ++rt)
      afr[rt] = *reinterpret_cast<const bf16x8*>(&xs[(rt * 16 + llo) * 264 + k0 + lhi * 8]);
#pragma unroll
    for (int nt = 0; nt < 4; ++nt)
      bfr[nt] = *reinterpret_cast<const bf16x8*>(&wl[(wid * 64 + nt * 16 + llo) * 56 + lhi * 8]);
#pragma unroll
    for (int rt = 0; rt < 4; ++rt)
#pragma unroll
      for (int nt = 0; nt < 4; ++nt)
        accv[rt][nt] = __builtin_amdgcn_mfma_f32_16x16x32_bf16(afr[rt], bfr[nt], accv[rt][nt], 0, 0, 0);
  }
}

// ---- per-relation: acc <- (W . acc) / deg, in place ----
__global__ __launch_bounds__(256) void rel_transform(
    float* __restrict__ acc, const unsigned short* __restrict__ Wbf,
    const float* __restrict__ deg) {
  __shared__ alignas(16) unsigned short xs[64 * 264];
  __shared__ alignas(16) unsigned short wl[256 * 56];
  __shared__ float dg[64];
  const int tid = threadIdx.x;
  const int r0 = blockIdx.x * 64;

  stage_x(acc, r0, xs, tid);
  if (tid < 64) { float d = deg[r0 + tid]; dg[tid] = (d == 0.f) ? 1.f : 1.f / d; }

  f32x4 accv[4][4];
#pragma unroll
  for (int a = 0; a < 4; ++a)
#pragma unroll
    for (int b = 0; b < 4; ++b) accv[a][b] = {0.f, 0.f, 0.f, 0.f};

  gemm_frag(xs, Wbf, wl, tid, accv);

  const int wid = tid >> 6, lane = tid & 63, lhi = lane >> 4, llo = lane & 15;
#pragma unroll
  for (int rt = 0; rt < 4; ++rt)
#pragma unroll
    for (int nt = 0; nt < 4; ++nt) {
      int col = wid * 64 + nt * 16 + llo;
#pragma unroll
      for (int rg = 0; rg < 4; ++rg) {
        int row = rt * 16 + lhi * 4 + rg;
        acc[(size_t)(r0 + row) * DIM + col] = accv[rt][nt][rg] * dg[row];
      }
    }
}

// ---- per node type: self-GEMM + relation attention + residual + LN + leaky ----
__global__ __launch_bounds__(256) void fuse_kernel(
    const float* __restrict__ h, const float* __restrict__ msg1,
    const float* __restrict__ msg2, const unsigned short* __restrict__ Wbf,
    const float* __restrict__ A1, const float* __restrict__ A2,
    const float* __restrict__ gamma, const float* __restrict__ beta,
    float* __restrict__ out) {
  __shared__ alignas(16) union SM {
    struct { unsigned short x[64 * 264]; unsigned short w[256 * 56]; } g;
    unsigned short s[64 * 260];  // self result, bf16
  } ov;
  __shared__ float sgb[512];
  const int tid = threadIdx.x;
  const int r0 = blockIdx.x * 64;

  stage_x(h, r0, ov.g.x, tid);
  for (int i = tid; i < 512; i += 256) sgb[i] = (i < 256) ? gamma[i] : beta[i - 256];

  f32x4 accv[4][4];
#pragma unroll
  for (int a = 0; a < 4; ++a)
#pragma unroll
    for (int b = 0; b < 4; ++b) accv[a][b] = {0.f, 0.f, 0.f, 0.f};

  gemm_frag(ov.g.x, Wbf, ov.g.w, tid, accv);

  const int wid = tid >> 6, lane = tid & 63, lhi = lane >> 4, llo = lane & 15;
  __syncthreads();  // all MFMA LDS reads done before overlaying ov.s
#pragma unroll
  for (int rt = 0; rt < 4; ++rt)
#pragma unroll
    for (int nt = 0; nt < 4; ++nt) {
      int col = wid * 64 + nt * 16 + llo;
#pragma unroll
      for (int rg = 0; rg < 4; ++rg)
        ov.s[(rt * 16 + lhi * 4 + rg) * 260 + col] = f2bf(accv[rt][nt][rg]);
    }
  __syncthreads();

  // epilogue: wave handles 16 rows; lane owns 4 dims
  const int d0 = lane * 4;
  const float4* A1v = reinterpret_cast<const float4*>(A1);
  const float4* A2v = reinterpret_cast<const float4*>(A2);
  float4 a1f[4], a2f[4];
#pragma unroll
  for (int hh = 0; hh < 4; ++hh) { a1f[hh] = A1v[hh * 64 + lane]; a2f[hh] = A2v[hh * 64 + lane]; }
  const float4 g4 = *reinterpret_cast<const float4*>(&sgb[d0]);
  const float4 b4 = *reinterpret_cast<const float4*>(&sgb[256 + d0]);

  for (int rl = 0; rl < 16; ++rl) {
    int row = wid * 16 + rl;
    size_t gb = (size_t)(r0 + row) * DIM + d0;
    float4 m1 = *reinterpret_cast<const float4*>(msg1 + gb);
    float4 m2 = *reinterpret_cast<const float4*>(msg2 + gb);
    float4 hv = *reinterpret_cast<const float4*>(h + gb);
    ushort4 sb = *reinterpret_cast<const ushort4*>(&ov.s[row * 260 + d0]);
    float4 sv = {bf2f(sb.x), bf2f(sb.y), bf2f(sb.z), bf2f(sb.w)};

    float sc[8];
#pragma unroll
    for (int hh = 0; hh < 4; ++hh) {
      sc[hh]     = m1.x * a1f[hh].x + m1.y * a1f[hh].y + m1.z * a1f[hh].z + m1.w * a1f[hh].w;
      sc[4 + hh] = m2.x * a2f[hh].x + m2.y * a2f[hh].y + m2.z * a2f[hh].z + m2.w * a2f[hh].w;
    }
#pragma unroll
    for (int o = 1; o < 64; o <<= 1) {
#pragma unroll
      for (int j = 0; j < 8; ++j) sc[j] += __shfl_xor(sc[j], o);
    }
    // softmax over the 2 relations per head; scale = 1/(sqrt(256)*0.5) = 0.125
    float c1 = 0.f, c2 = 0.f;
#pragma unroll
    for (int hh = 0; hh < 4; ++hh) {
      float s1 = sc[hh] * 0.125f, s2 = sc[4 + hh] * 0.125f;
      float mx = fmaxf(s1, s2);
      float e1 = __expf(s1 - mx), e2 = __expf(s2 - mx);
      float inv = 1.f / (e1 + e2);
      c1 += e1 * inv; c2 += e2 * inv;
    }
    c1 *= 0.25f; c2 *= 0.25f;  // mean over H=4 heads

    float4 u;
    u.x = sv.x + c1 * m1.x + c2 * m2.x + hv.x;
    u.y = sv.y + c1 * m1.y + c2 * m2.y + hv.y;
    u.z = sv.z + c1 * m1.z + c2 * m2.z + hv.z;
    u.w = sv.w + c1 * m1.w + c2 * m2.w + hv.w;

    float s1v = u.x + u.y + u.z + u.w;
    float s2v = u.x * u.x + u.y * u.y + u.z * u.z + u.w * u.w;
#pragma unroll
    for (int o = 1; o < 64; o <<= 1) { s1v += __shfl_xor(s1v, o); s2v += __shfl_xor(s2v, o); }
    float mu = s1v * (1.f / 256.f);
    float var = s2v * (1.f / 256.f) - mu * mu;
    float rstd = rsqrtf(var + 1e-5f);

    float4 y;
    y.x = (u.x - mu) * rstd * g4.x + b4.x;
    y.y = (u.y - mu) * rstd * g4.y + b4.y;
    y.z = (u.z - mu) * rstd * g4.z + b4.z;
    y.w = (u.w - mu) * rstd * g4.w + b4.w;
    y.x = fmaxf(y.x, 0.01f * y.x);
    y.y = fmaxf(y.y, 0.01f * y.y);
    y.z = fmaxf(y.z, 0.01f * y.z);
    y.w = fmaxf(y.w, 0.01f * y.w);
    *reinterpret_cast<float4*>(out + gb) = y;
  }
}

// ---- workspace layout (float offsets) ----
static constexpr size_t ACC_L2G = 0;
static constexpr size_t ACC_G2L = ACC_L2G + (size_t)NGr * DIM;
static constexpr size_t ACC_G2D = ACC_G2L + (size_t)NLr * DIM;
static constexpr size_t ACC_D2G = ACC_G2D + (size_t)NDr * DIM;
static constexpr size_t ACC_L2D = ACC_D2G + (size_t)NGr * DIM;
static constexpr size_t ACC_D2L = ACC_L2D + (size_t)NDr * DIM;
static constexpr size_t DEG_L2G = ACC_D2L + (size_t)NLr * DIM;
static constexpr size_t DEG_G2L = DEG_L2G + NGr;
static constexpr size_t DEG_G2D = DEG_G2L + NLr;
static constexpr size_t DEG_D2G = DEG_G2D + NDr;
static constexpr size_t DEG_L2D = DEG_D2G + NGr;
static constexpr size_t DEG_D2L = DEG_L2D + NDr;
static constexpr size_t ZERO_FLOATS = DEG_D2L + NLr;
static constexpr size_t WBF_OFF_BYTES = ZERO_FLOATS * sizeof(float);

extern "C" void kernel_launch(void* const* d_in, const int* in_sizes, int n_in,
                              void* d_out, int out_size, void* d_ws, size_t ws_size,
                              hipStream_t stream) {
  float* ws = (float*)d_ws;
  unsigned short* wbf = (unsigned short*)((char*)d_ws + WBF_OFF_BYTES);
  float* out = (float*)d_out;

  // zero accumulators + degrees every call (harness does not re-poison)
  (void)hipMemsetAsync(d_ws, 0, ZERO_FLOATS * sizeof(float), stream);

  // convert weights to bf16: slots 0..5 = W_{l2g,g2l,g2d,d2g,l2d,d2l}, 6..8 = Wself_{l,g,d}
  WPtrs wp;
  wp.p[0] = (const float*)d_in[6];  wp.p[1] = (const float*)d_in[11];
  wp.p[2] = (const float*)d_in[16]; wp.p[3] = (const float*)d_in[21];
  wp.p[4] = (const float*)d_in[26]; wp.p[5] = (const float*)d_in[31];
  wp.p[6] = (const float*)d_in[33]; wp.p[7] = (const float*)d_in[36];
  wp.p[8] = (const float*)d_in[39];
  conv_w_kernel<<<dim3(256, 9), 256, 0, stream>>>(wp, wbf);

  auto SC = [&](int hi, int base, size_t accOff, size_t degOff) {
    scatter_kernel<<<NE / 4, 256, 0, stream>>>(
        (const float*)d_in[hi], (const int*)d_in[base], (const int*)d_in[base + 1],
        (const float*)d_in[base + 2], ws + accOff, ws + degOff);
  };
  SC(0, 3,  ACC_L2G, DEG_L2G);  // l2g: src h_l
  SC(1, 8,  ACC_G2L, DEG_G2L);  // g2l: src h_g
  SC(1, 13, ACC_G2D, DEG_G2D);  // g2d: src h_g
  SC(2, 18, ACC_D2G, DEG_D2G);  // d2g: src h_d
  SC(0, 23, ACC_L2D, DEG_L2D);  // l2d: src h_l
  SC(2, 28, ACC_D2L, DEG_D2L);  // d2l: src h_d

  rel_transform<<<NGr / 64, 256, 0, stream>>>(ws + ACC_L2G, wbf + 0 * 65536, ws + DEG_L2G);
  rel_transform<<<NLr / 64, 256, 0, stream>>>(ws + ACC_G2L, wbf + 1 * 65536, ws + DEG_G2L);
  rel_transform<<<NDr / 64, 256, 0, stream>>>(ws + ACC_G2D, wbf + 2 * 65536, ws + DEG_G2D);
  rel_transform<<<NGr / 64, 256, 0, stream>>>(ws + ACC_D2G, wbf + 3 * 65536, ws + DEG_D2G);
  rel_transform<<<NDr / 64, 256, 0, stream>>>(ws + ACC_L2D, wbf + 4 * 65536, ws + DEG_L2D);
  rel_transform<<<NLr / 64, 256, 0, stream>>>(ws + ACC_D2L, wbf + 5 * 65536, ws + DEG_D2L);

  // type l: msgs [g2l, d2l]
  fuse_kernel<<<NLr / 64, 256, 0, stream>>>(
      (const float*)d_in[0], ws + ACC_G2L, ws + ACC_D2L, wbf + 6 * 65536,
      (const float*)d_in[12], (const float*)d_in[32],
      (const float*)d_in[34], (const float*)d_in[35], out);
  // type g: msgs [l2g, d2g]
  fuse_kernel<<<NGr / 64, 256, 0, stream>>>(
      (const float*)d_in[1], ws + ACC_L2G, ws + ACC_D2G, wbf + 7 * 65536,
      (const float*)d_in[7], (const float*)d_in[22],
      (const float*)d_in[37], (const float*)d_in[38], out + (size_t)NLr * DIM);
  // type d: msgs [g2d, l2d]
  fuse_kernel<<<NDr / 64, 256, 0, stream>>>(
      (const float*)d_in[2], ws + ACC_G2D, ws + ACC_L2D, wbf + 8 * 65536,
      (const float*)d_in[17], (const float*)d_in[27],
      (const float*)d_in[40], (const float*)d_in[41], out + (size_t)(NLr + NGr) * DIM);
}

// Round 2
// 647.206 us; speedup vs baseline: 8.5419x; 8.5419x over previous
//
#include <hip/hip_runtime.h>

#define DIM 256
#define NLr 16384
#define NGr 32768
#define NDr 8192
#define NE  262144

typedef short bf16x8 __attribute__((ext_vector_type(8)));
typedef float f32x4 __attribute__((ext_vector_type(4)));

__device__ __forceinline__ unsigned short f2bf(float f) {
  unsigned int u = __builtin_bit_cast(unsigned int, f);
  u += 0x7fffu + ((u >> 16) & 1u);
  return (unsigned short)(u >> 16);
}
__device__ __forceinline__ float bf2f(unsigned short b) {
  return __builtin_bit_cast(float, ((unsigned int)b) << 16);
}

struct WPtrs { const float* p[9]; };
struct RelIdx { const int* dst[6]; int n[6]; };

// ---- convert 9 weight matrices (f32 -> bf16), 65536 elems each ----
__global__ __launch_bounds__(256) void conv_w_kernel(WPtrs wp, unsigned short* __restrict__ dst) {
  int m = blockIdx.y;
  int i = blockIdx.x * 256 + threadIdx.x;
  dst[m * 65536 + i] = f2bf(wp.p[m][i]);
}

// ---- CSR build: histogram over dst for all 6 relations ----
__global__ __launch_bounds__(256) void hist6_kernel(RelIdx R, int* __restrict__ hist) {
  int r = blockIdx.y;
  int e = blockIdx.x * 256 + threadIdx.x;
  atomicAdd(&hist[r * 32769 + R.dst[r][e]], 1);
}

// ---- CSR build: per-relation exclusive scan (one block per relation) ----
__global__ __launch_bounds__(1024) void scan6_kernel(RelIdx R, const int* __restrict__ hist,
                                                     int* __restrict__ offs, int* __restrict__ cursor) {
  __shared__ int part[1024];
  const int r = blockIdx.x;
  const int n = R.n[r];
  const int* h = hist + r * 32769;
  int* o = offs + r * 32769;
  int* c = cursor + r * 32768;
  const int tid = threadIdx.x;
  const int chunk = (n + 1023) >> 10;
  const int base = tid * chunk;
  int s = 0;
  for (int j = 0; j < chunk; ++j) { int idx = base + j; if (idx < n) s += h[idx]; }
  part[tid] = s;
  __syncthreads();
  for (int off = 1; off < 1024; off <<= 1) {
    int v = (tid >= off) ? part[tid - off] : 0;
    __syncthreads();
    part[tid] += v;
    __syncthreads();
  }
  int run = part[tid] - s;  // exclusive prefix of this thread's chunk
  for (int j = 0; j < chunk; ++j) {
    int idx = base + j;
    if (idx < n) { o[idx] = run; run += h[idx]; c[idx] = 0; }
  }
  if (tid == 1023) o[n] = run;  // == NE
}

// ---- CSR build: bucket-scatter packed (src, w) pairs ----
__global__ __launch_bounds__(256) void scatter_eid_kernel(
    const int* __restrict__ src, const int* __restrict__ dst,
    const float* __restrict__ w, const int* __restrict__ offs,
    int* __restrict__ cursor, int2* __restrict__ srcw) {
  int e = blockIdx.x * 256 + threadIdx.x;
  int d = dst[e];
  int pos = offs[d] + atomicAdd(&cursor[d], 1);
  srcw[pos] = make_int2(src[e], __builtin_bit_cast(int, w[e]));
}

// ---- gather: acc[node] = (sum_e w_e * h_src[src_e]) / deg, one wave per node ----
__global__ __launch_bounds__(256) void gather_kernel(
    const float* __restrict__ hsrc, const int2* __restrict__ srcw,
    const int* __restrict__ offs, float* __restrict__ acc) {
  const int node = blockIdx.x * 4 + (threadIdx.x >> 6);
  const int lane = threadIdx.x & 63;
  const int beg = offs[node], end = offs[node + 1];
  const float4* __restrict__ hv = reinterpret_cast<const float4*>(hsrc);
  float4 a = {0.f, 0.f, 0.f, 0.f};
  float degw = 0.f;
  int j = beg;
  for (; j + 1 < end; j += 2) {
    int2 p0 = srcw[j], p1 = srcw[j + 1];
    float w0 = __builtin_bit_cast(float, p0.y);
    float w1 = __builtin_bit_cast(float, p1.y);
    float4 x0 = hv[(size_t)p0.x * 64 + lane];
    float4 x1 = hv[(size_t)p1.x * 64 + lane];
    degw += w0 + w1;
    a.x += w0 * x0.x + w1 * x1.x;
    a.y += w0 * x0.y + w1 * x1.y;
    a.z += w0 * x0.z + w1 * x1.z;
    a.w += w0 * x0.w + w1 * x1.w;
  }
  if (j < end) {
    int2 p0 = srcw[j];
    float w0 = __builtin_bit_cast(float, p0.y);
    float4 x0 = hv[(size_t)p0.x * 64 + lane];
    degw += w0;
    a.x += w0 * x0.x; a.y += w0 * x0.y; a.z += w0 * x0.z; a.w += w0 * x0.w;
  }
  float inv = (degw == 0.f) ? 1.f : 1.f / degw;
  float4 o = {a.x * inv, a.y * inv, a.z * inv, a.w * inv};
  reinterpret_cast<float4*>(acc)[(size_t)node * 64 + lane] = o;
}

// ---- shared GEMM pieces: 64 rows x (256x256) bf16 MFMA ----
__device__ __forceinline__ void stage_x(const float* __restrict__ g, int r0,
                                        unsigned short* xs, int tid) {
#pragma unroll
  for (int it = 0; it < 16; ++it) {
    int i = it * 256 + tid;
    int row = i >> 6, q = i & 63;
    float4 v = reinterpret_cast<const float4*>(g)[(size_t)(r0 + row) * 64 + q];
    ushort4 b;
    b.x = f2bf(v.x); b.y = f2bf(v.y); b.z = f2bf(v.z); b.w = f2bf(v.w);
    *reinterpret_cast<ushort4*>(&xs[row * 264 + q * 4]) = b;
  }
}

__device__ __forceinline__ void gemm_frag(const unsigned short* xs,
                                          const unsigned short* __restrict__ Wg,
                                          unsigned short* wl, int tid,
                                          f32x4 accv[4][4]) {
  const int wid = tid >> 6, lhi = (tid & 63) >> 4, llo = tid & 15;
  for (int ks = 0; ks < 8; ++ks) {
    const int k0 = ks * 32;
    __syncthreads();  // protects xs (first iter) and wl reads from prev iter
    {
      const uint4* gp = reinterpret_cast<const uint4*>(Wg + (size_t)tid * 256 + k0);
      uint4 a0 = gp[0], a1 = gp[1], a2 = gp[2], a3 = gp[3];
      uint4* lp = reinterpret_cast<uint4*>(wl + tid * 56);
      lp[0] = a0; lp[1] = a1; lp[2] = a2; lp[3] = a3;
    }
    __syncthreads();
    bf16x8 afr[4], bfr[4];
#pragma unroll
    for (int rt = 0; rt < 4; ++rt)
      afr[rt] = *reinterpret_cast<const bf16x8*>(&xs[(rt * 16 + llo) * 264 + k0 + lhi * 8]);
#pragma unroll
    for (int nt = 0; nt < 4; ++nt)
      bfr[nt] = *reinterpret_cast<const bf16x8*>(&wl[(wid * 64 + nt * 16 + llo) * 56 + lhi * 8]);
#pragma unroll
    for (int rt = 0; rt < 4; ++rt)
#pragma unroll
      for (int nt = 0; nt < 4; ++nt)
        accv[rt][nt] = __builtin_amdgcn_mfma_f32_16x16x32_bf16(afr[rt], bfr[nt], accv[rt][nt], 0, 0, 0);
  }
}

// ---- per-relation: acc <- W . acc, in place (deg already folded in gather) ----
__global__ __launch_bounds__(256) void rel_transform(
    float* __restrict__ acc, const unsigned short* __restrict__ Wbf) {
  __shared__ alignas(16) unsigned short xs[64 * 264];
  __shared__ alignas(16) unsigned short wl[256 * 56];
  const int tid = threadIdx.x;
  const int r0 = blockIdx.x * 64;

  stage_x(acc, r0, xs, tid);

  f32x4 accv[4][4];
#pragma unroll
  for (int a = 0; a < 4; ++a)
#pragma unroll
    for (int b = 0; b < 4; ++b) accv[a][b] = {0.f, 0.f, 0.f, 0.f};

  gemm_frag(xs, Wbf, wl, tid, accv);

  const int wid = tid >> 6, lane = tid & 63, lhi = lane >> 4, llo = lane & 15;
#pragma unroll
  for (int rt = 0; rt < 4; ++rt)
#pragma unroll
    for (int nt = 0; nt < 4; ++nt) {
      int col = wid * 64 + nt * 16 + llo;
#pragma unroll
      for (int rg = 0; rg < 4; ++rg) {
        int row = rt * 16 + lhi * 4 + rg;
        acc[(size_t)(r0 + row) * DIM + col] = accv[rt][nt][rg];
      }
    }
}

// ---- per node type: self-GEMM + relation attention + residual + LN + leaky ----
__global__ __launch_bounds__(256) void fuse_kernel(
    const float* __restrict__ h, const float* __restrict__ msg1,
    const float* __restrict__ msg2, const unsigned short* __restrict__ Wbf,
    const float* __restrict__ A1, const float* __restrict__ A2,
    const float* __restrict__ gamma, const float* __restrict__ beta,
    float* __restrict__ out) {
  __shared__ alignas(16) union SM {
    struct { unsigned short x[64 * 264]; unsigned short w[256 * 56]; } g;
    unsigned short s[64 * 260];  // self result, bf16
  } ov;
  __shared__ float sgb[512];
  const int tid = threadIdx.x;
  const int r0 = blockIdx.x * 64;

  stage_x(h, r0, ov.g.x, tid);
  for (int i = tid; i < 512; i += 256) sgb[i] = (i < 256) ? gamma[i] : beta[i - 256];

  f32x4 accv[4][4];
#pragma unroll
  for (int a = 0; a < 4; ++a)
#pragma unroll
    for (int b = 0; b < 4; ++b) accv[a][b] = {0.f, 0.f, 0.f, 0.f};

  gemm_frag(ov.g.x, Wbf, ov.g.w, tid, accv);

  const int wid = tid >> 6, lane = tid & 63, lhi = lane >> 4, llo = lane & 15;
  __syncthreads();  // all MFMA LDS reads done before overlaying ov.s
#pragma unroll
  for (int rt = 0; rt < 4; ++rt)
#pragma unroll
    for (int nt = 0; nt < 4; ++nt) {
      int col = wid * 64 + nt * 16 + llo;
#pragma unroll
      for (int rg = 0; rg < 4; ++rg)
        ov.s[(rt * 16 + lhi * 4 + rg) * 260 + col] = f2bf(accv[rt][nt][rg]);
    }
  __syncthreads();

  // epilogue: wave handles 16 rows; lane owns 4 dims
  const int d0 = lane * 4;
  const float4* A1v = reinterpret_cast<const float4*>(A1);
  const float4* A2v = reinterpret_cast<const float4*>(A2);
  float4 a1f[4], a2f[4];
#pragma unroll
  for (int hh = 0; hh < 4; ++hh) { a1f[hh] = A1v[hh * 64 + lane]; a2f[hh] = A2v[hh * 64 + lane]; }
  const float4 g4 = *reinterpret_cast<const float4*>(&sgb[d0]);
  const float4 b4 = *reinterpret_cast<const float4*>(&sgb[256 + d0]);

  for (int rl = 0; rl < 16; ++rl) {
    int row = wid * 16 + rl;
    size_t gb = (size_t)(r0 + row) * DIM + d0;
    float4 m1 = *reinterpret_cast<const float4*>(msg1 + gb);
    float4 m2 = *reinterpret_cast<const float4*>(msg2 + gb);
    float4 hvv = *reinterpret_cast<const float4*>(h + gb);
    ushort4 sb = *reinterpret_cast<const ushort4*>(&ov.s[row * 260 + d0]);
    float4 sv = {bf2f(sb.x), bf2f(sb.y), bf2f(sb.z), bf2f(sb.w)};

    float sc[8];
#pragma unroll
    for (int hh = 0; hh < 4; ++hh) {
      sc[hh]     = m1.x * a1f[hh].x + m1.y * a1f[hh].y + m1.z * a1f[hh].z + m1.w * a1f[hh].w;
      sc[4 + hh] = m2.x * a2f[hh].x + m2.y * a2f[hh].y + m2.z * a2f[hh].z + m2.w * a2f[hh].w;
    }
#pragma unroll
    for (int o = 1; o < 64; o <<= 1) {
#pragma unroll
      for (int j = 0; j < 8; ++j) sc[j] += __shfl_xor(sc[j], o);
    }
    // softmax over the 2 relations per head; scale = 1/(sqrt(256)*0.5) = 0.125
    float c1 = 0.f, c2 = 0.f;
#pragma unroll
    for (int hh = 0; hh < 4; ++hh) {
      float s1 = sc[hh] * 0.125f, s2 = sc[4 + hh] * 0.125f;
      float mx = fmaxf(s1, s2);
      float e1 = __expf(s1 - mx), e2 = __expf(s2 - mx);
      float inv = 1.f / (e1 + e2);
      c1 += e1 * inv; c2 += e2 * inv;
    }
    c1 *= 0.25f; c2 *= 0.25f;  // mean over H=4 heads

    float4 u;
    u.x = sv.x + c1 * m1.x + c2 * m2.x + hvv.x;
    u.y = sv.y + c1 * m1.y + c2 * m2.y + hvv.y;
    u.z = sv.z + c1 * m1.z + c2 * m2.z + hvv.z;
    u.w = sv.w + c1 * m1.w + c2 * m2.w + hvv.w;

    float s1v = u.x + u.y + u.z + u.w;
    float s2v = u.x * u.x + u.y * u.y + u.z * u.z + u.w * u.w;
#pragma unroll
    for (int o = 1; o < 64; o <<= 1) { s1v += __shfl_xor(s1v, o); s2v += __shfl_xor(s2v, o); }
    float mu = s1v * (1.f / 256.f);
    float var = s2v * (1.f / 256.f) - mu * mu;
    float rstd = rsqrtf(var + 1e-5f);

    float4 y;
    y.x = (u.x - mu) * rstd * g4.x + b4.x;
    y.y = (u.y - mu) * rstd * g4.y + b4.y;
    y.z = (u.z - mu) * rstd * g4.z + b4.z;
    y.w = (u.w - mu) * rstd * g4.w + b4.w;
    y.x = fmaxf(y.x, 0.01f * y.x);
    y.y = fmaxf(y.y, 0.01f * y.y);
    y.z = fmaxf(y.z, 0.01f * y.z);
    y.w = fmaxf(y.w, 0.01f * y.w);
    *reinterpret_cast<float4*>(out + gb) = y;
  }
}

// ---- workspace layout ----
static constexpr size_t ACC_L2G = 0;
static constexpr size_t ACC_G2L = ACC_L2G + (size_t)NGr * DIM;
static constexpr size_t ACC_G2D = ACC_G2L + (size_t)NLr * DIM;
static constexpr size_t ACC_D2G = ACC_G2D + (size_t)NDr * DIM;
static constexpr size_t ACC_L2D = ACC_D2G + (size_t)NGr * DIM;
static constexpr size_t ACC_D2L = ACC_L2D + (size_t)NDr * DIM;
static constexpr size_t ACC_FLOATS = ACC_D2L + (size_t)NLr * DIM;
static constexpr size_t WBF_BYTE_OFF = ACC_FLOATS * 4;                      // bf16 weights
static constexpr size_t HIST_BYTE_OFF = WBF_BYTE_OFF + 9 * 65536 * 2;       // 6 x 32769 ints
static constexpr size_t OFFS_BYTE_OFF = HIST_BYTE_OFF + 6 * 32769 * 4;      // 6 x 32769 ints
static constexpr size_t CURS_BYTE_OFF = OFFS_BYTE_OFF + 6 * 32769 * 4;      // 6 x 32768 ints
static constexpr size_t SRCW_BYTE_OFF = CURS_BYTE_OFF + 6 * 32768 * 4;      // NE x int2 (shared)

extern "C" void kernel_launch(void* const* d_in, const int* in_sizes, int n_in,
                              void* d_out, int out_size, void* d_ws, size_t ws_size,
                              hipStream_t stream) {
  float* ws = (float*)d_ws;
  unsigned short* wbf = (unsigned short*)((char*)d_ws + WBF_BYTE_OFF);
  int* hist = (int*)((char*)d_ws + HIST_BYTE_OFF);
  int* offs = (int*)((char*)d_ws + OFFS_BYTE_OFF);
  int* curs = (int*)((char*)d_ws + CURS_BYTE_OFF);
  int2* srcw = (int2*)((char*)d_ws + SRCW_BYTE_OFF);
  float* out = (float*)d_out;

  // relation order: l2g, g2l, g2d, d2g, l2d, d2l
  const int base[6] = {3, 8, 13, 18, 23, 28};
  const int hidx[6] = {0, 1, 1, 2, 0, 2};
  const int ndst[6] = {NGr, NLr, NDr, NGr, NDr, NLr};
  const size_t accOff[6] = {ACC_L2G, ACC_G2L, ACC_G2D, ACC_D2G, ACC_L2D, ACC_D2L};

  // convert weights to bf16: slots 0..5 = W_rel, 6..8 = Wself_{l,g,d}
  WPtrs wp;
  wp.p[0] = (const float*)d_in[6];  wp.p[1] = (const float*)d_in[11];
  wp.p[2] = (const float*)d_in[16]; wp.p[3] = (const float*)d_in[21];
  wp.p[4] = (const float*)d_in[26]; wp.p[5] = (const float*)d_in[31];
  wp.p[6] = (const float*)d_in[33]; wp.p[7] = (const float*)d_in[36];
  wp.p[8] = (const float*)d_in[39];
  conv_w_kernel<<<dim3(256, 9), 256, 0, stream>>>(wp, wbf);

  // CSR build (batched)
  (void)hipMemsetAsync(hist, 0, 6 * 32769 * 4, stream);
  RelIdx R;
  for (int r = 0; r < 6; ++r) { R.dst[r] = (const int*)d_in[base[r] + 1]; R.n[r] = ndst[r]; }
  hist6_kernel<<<dim3(NE / 256, 6), 256, 0, stream>>>(R, hist);
  scan6_kernel<<<6, 1024, 0, stream>>>(R, hist, offs, curs);

  // per relation: bucket-scatter + gather (srcw buffer reused serially)
  for (int r = 0; r < 6; ++r) {
    scatter_eid_kernel<<<NE / 256, 256, 0, stream>>>(
        (const int*)d_in[base[r]], (const int*)d_in[base[r] + 1],
        (const float*)d_in[base[r] + 2], offs + r * 32769, curs + r * 32768, srcw);
    gather_kernel<<<ndst[r] / 4, 256, 0, stream>>>(
        (const float*)d_in[hidx[r]], srcw, offs + r * 32769, ws + accOff[r]);
  }

  rel_transform<<<NGr / 64, 256, 0, stream>>>(ws + ACC_L2G, wbf + 0 * 65536);
  rel_transform<<<NLr / 64, 256, 0, stream>>>(ws + ACC_G2L, wbf + 1 * 65536);
  rel_transform<<<NDr / 64, 256, 0, stream>>>(ws + ACC_G2D, wbf + 2 * 65536);
  rel_transform<<<NGr / 64, 256, 0, stream>>>(ws + ACC_D2G, wbf + 3 * 65536);
  rel_transform<<<NDr / 64, 256, 0, stream>>>(ws + ACC_L2D, wbf + 4 * 65536);
  rel_transform<<<NLr / 64, 256, 0, stream>>>(ws + ACC_D2L, wbf + 5 * 65536);

  // type l: msgs [g2l, d2l]
  fuse_kernel<<<NLr / 64, 256, 0, stream>>>(
      (const float*)d_in[0], ws + ACC_G2L, ws + ACC_D2L, wbf + 6 * 65536,
      (const float*)d_in[12], (const float*)d_in[32],
      (const float*)d_in[34], (const float*)d_in[35], out);
  // type g: msgs [l2g, d2g]
  fuse_kernel<<<NGr / 64, 256, 0, stream>>>(
      (const float*)d_in[1], ws + ACC_L2G, ws + ACC_D2G, wbf + 7 * 65536,
      (const float*)d_in[7], (const float*)d_in[22],
      (const float*)d_in[37], (const float*)d_in[38], out + (size_t)NLr * DIM);
  // type d: msgs [g2d, l2d]
  fuse_kernel<<<NDr / 64, 256, 0, stream>>>(
      (const float*)d_in[2], ws + ACC_G2D, ws + ACC_L2D, wbf + 8 * 65536,
      (const float*)d_in[17], (const float*)d_in[27],
      (const float*)d_in[40], (const float*)d_in[41], out + (size_t)(NLr + NGr) * DIM);
}

// Round 3
// 450.472 us; speedup vs baseline: 12.2723x; 1.4367x over previous
//
#include <hip/hip_runtime.h>

#define DIM 256
#define NLr 16384
#define NGr 32768
#define NDr 8192
#define NE  262144
#define HSTRIDE 32772  // hist/offs per-relation stride (16B-aligned)

typedef short bf16x8 __attribute__((ext_vector_type(8)));
typedef float f32x4 __attribute__((ext_vector_type(4)));

__device__ __forceinline__ unsigned short f2bf(float f) {
  unsigned int u = __builtin_bit_cast(unsigned int, f);
  u += 0x7fffu + ((u >> 16) & 1u);
  return (unsigned short)(u >> 16);
}
__device__ __forceinline__ float bf2f(unsigned short b) {
  return __builtin_bit_cast(float, ((unsigned int)b) << 16);
}
__device__ __forceinline__ float bflo(unsigned int u) {
  return __builtin_bit_cast(float, u << 16);
}
__device__ __forceinline__ float bfhi(unsigned int u) {
  return __builtin_bit_cast(float, u & 0xffff0000u);
}

struct WPtrs { const float* p[9]; };
struct H3 { const float* h[3]; int cnt4[3]; int obase[3]; };
struct NTab { int n[6]; };
struct RelIdx { const int* dst[6]; };
struct ETab { const int* src[6]; const int* dst[6]; const float* w[6]; };
struct GTab { const unsigned short* hb[6]; unsigned short* acc[6];
              const int2* sw[6]; const int* of[6]; int cum[7]; };
struct RTab { unsigned short* acc[6]; int cum[7]; };

// ---- convert 9 weight matrices (f32 -> bf16), 65536 elems each ----
__global__ __launch_bounds__(256) void conv_w_kernel(WPtrs wp, unsigned short* __restrict__ dst) {
  int m = blockIdx.y;
  int i = blockIdx.x * 256 + threadIdx.x;
  dst[m * 65536 + i] = f2bf(wp.p[m][i]);
}

// ---- convert h_l,h_g,h_d to bf16 ----
__global__ __launch_bounds__(256) void h2bf_kernel(H3 X, unsigned short* __restrict__ hbf) {
  int t = blockIdx.y;
  const float4* sv = reinterpret_cast<const float4*>(X.h[t]);
  uint2* ob = reinterpret_cast<uint2*>(hbf) + X.obase[t];
  unsigned cnt = X.cnt4[t];
  for (unsigned i = blockIdx.x * 256 + threadIdx.x; i < cnt; i += gridDim.x * 256) {
    float4 v = sv[i];
    uint2 o;
    o.x = (unsigned)f2bf(v.x) | ((unsigned)f2bf(v.y) << 16);
    o.y = (unsigned)f2bf(v.z) | ((unsigned)f2bf(v.w) << 16);
    ob[i] = o;
  }
}

// ---- CSR build: histogram over dst for all 6 relations ----
__global__ __launch_bounds__(256) void hist6_kernel(RelIdx R, int* __restrict__ hist) {
  int r = blockIdx.y;
  int e = blockIdx.x * 256 + threadIdx.x;
  atomicAdd(&hist[r * HSTRIDE + R.dst[r][e]], 1);
}

// ---- scan stage A: per-block partial sums (4096 bins / block) ----
__global__ __launch_bounds__(256) void scanA_kernel(const int* __restrict__ hist,
                                                    int* __restrict__ partials, NTab N) {
  int r = blockIdx.y, b = blockIdx.x;
  int n = N.n[r], base = b * 4096;
  int s = 0;
  if (base < n) {
    const int4* h4 = reinterpret_cast<const int4*>(hist + r * HSTRIDE + base);
#pragma unroll
    for (int k = 0; k < 4; ++k) {
      int4 v = h4[threadIdx.x * 4 + k];
      s += v.x + v.y + v.z + v.w;
    }
  }
#pragma unroll
  for (int o = 1; o < 64; o <<= 1) s += __shfl_xor(s, o);
  __shared__ int wsum[4];
  if ((threadIdx.x & 63) == 0) wsum[threadIdx.x >> 6] = s;
  __syncthreads();
  if (threadIdx.x == 0) partials[r * 8 + b] = wsum[0] + wsum[1] + wsum[2] + wsum[3];
}

// ---- scan stage B: tiny per-relation exclusive scan of 8 partials ----
__global__ void scanTop_kernel(const int* __restrict__ partials, int* __restrict__ boff) {
  int r = threadIdx.x;
  if (r < 6) {
    int off = 0;
    for (int b = 0; b < 8; ++b) { boff[r * 8 + b] = off; off += partials[r * 8 + b]; }
  }
}

// ---- scan stage C: block-local scan + write offs, zero cursor ----
__global__ __launch_bounds__(256) void scanC_kernel(const int* __restrict__ hist,
                                                    const int* __restrict__ boff,
                                                    int* __restrict__ offs,
                                                    int* __restrict__ cursor, NTab N) {
  int r = blockIdx.y, b = blockIdx.x;
  int n = N.n[r], base = b * 4096;
  if (base >= n) return;
  const int tid = threadIdx.x;
  int vals[16];
  int s = 0;
  const int4* h4 = reinterpret_cast<const int4*>(hist + r * HSTRIDE + base);
#pragma unroll
  for (int k = 0; k < 4; ++k) {
    int4 v = h4[tid * 4 + k];
    vals[4 * k] = v.x; vals[4 * k + 1] = v.y; vals[4 * k + 2] = v.z; vals[4 * k + 3] = v.w;
    s += v.x + v.y + v.z + v.w;
  }
  __shared__ int part[256];
  part[tid] = s;
  __syncthreads();
  for (int off = 1; off < 256; off <<= 1) {
    int v = (tid >= off) ? part[tid - off] : 0;
    __syncthreads();
    part[tid] += v;
    __syncthreads();
  }
  int run = part[tid] - s + boff[r * 8 + b];
  int gbase = base + tid * 16;
#pragma unroll
  for (int j = 0; j < 16; ++j) {
    offs[r * HSTRIDE + gbase + j] = run;
    run += vals[j];
    cursor[r * 32768 + gbase + j] = 0;
  }
  if (b == 0 && tid == 0) offs[r * HSTRIDE + n] = NE;
}

// ---- CSR build: bucket-scatter packed (src, w) pairs, all 6 relations ----
__global__ __launch_bounds__(256) void scatter6_kernel(ETab E, const int* __restrict__ offs,
                                                       int* __restrict__ cursor,
                                                       int2* __restrict__ srcw) {
  int r = blockIdx.y;
  int e = blockIdx.x * 256 + threadIdx.x;
  int d = E.dst[r][e];
  int pos = offs[r * HSTRIDE + d] + atomicAdd(&cursor[r * 32768 + d], 1);
  srcw[(size_t)r * NE + pos] = make_int2(E.src[r][e], __builtin_bit_cast(int, E.w[r][e]));
}

// ---- gather: acc[node] = (sum w_e * hb[src_e]) / deg, one wave per node, bf16 ----
__global__ __launch_bounds__(256) void gather6_kernel(GTab T) {
  const int bx = blockIdx.x;
  int r = 0;
#pragma unroll
  for (int k = 1; k < 6; ++k) r += (bx >= T.cum[k]);
  const int node = (bx - T.cum[r]) * 4 + (threadIdx.x >> 6);
  const int lane = threadIdx.x & 63;
  const int* of = T.of[r];
  const int beg = of[node], end = of[node + 1];
  const uint2* __restrict__ hv = reinterpret_cast<const uint2*>(T.hb[r]);
  const int2* __restrict__ sw = T.sw[r];
  float4 a = {0.f, 0.f, 0.f, 0.f};
  float degw = 0.f;
  int j = beg;
  for (; j + 1 < end; j += 2) {
    int2 p0 = sw[j], p1 = sw[j + 1];
    float w0 = __builtin_bit_cast(float, p0.y);
    float w1 = __builtin_bit_cast(float, p1.y);
    uint2 x0 = hv[(size_t)p0.x * 64 + lane];
    uint2 x1 = hv[(size_t)p1.x * 64 + lane];
    degw += w0 + w1;
    a.x += w0 * bflo(x0.x) + w1 * bflo(x1.x);
    a.y += w0 * bfhi(x0.x) + w1 * bfhi(x1.x);
    a.z += w0 * bflo(x0.y) + w1 * bflo(x1.y);
    a.w += w0 * bfhi(x0.y) + w1 * bfhi(x1.y);
  }
  if (j < end) {
    int2 p0 = sw[j];
    float w0 = __builtin_bit_cast(float, p0.y);
    uint2 x0 = hv[(size_t)p0.x * 64 + lane];
    degw += w0;
    a.x += w0 * bflo(x0.x); a.y += w0 * bfhi(x0.x);
    a.z += w0 * bflo(x0.y); a.w += w0 * bfhi(x0.y);
  }
  float inv = (degw == 0.f) ? 1.f : 1.f / degw;
  uint2 o;
  o.x = (unsigned)f2bf(a.x * inv) | ((unsigned)f2bf(a.y * inv) << 16);
  o.y = (unsigned)f2bf(a.z * inv) | ((unsigned)f2bf(a.w * inv) << 16);
  reinterpret_cast<uint2*>(T.acc[r])[(size_t)node * 64 + lane] = o;
}

// ---- shared GEMM pieces: 64 rows x (256x256) bf16 MFMA ----
__device__ __forceinline__ void stage_x_f32(const float* __restrict__ g, int r0,
                                            unsigned short* xs, int tid) {
#pragma unroll
  for (int it = 0; it < 16; ++it) {
    int i = it * 256 + tid;
    int row = i >> 6, q = i & 63;
    float4 v = reinterpret_cast<const float4*>(g)[(size_t)(r0 + row) * 64 + q];
    ushort4 b;
    b.x = f2bf(v.x); b.y = f2bf(v.y); b.z = f2bf(v.z); b.w = f2bf(v.w);
    *reinterpret_cast<ushort4*>(&xs[row * 264 + q * 4]) = b;
  }
}

__device__ __forceinline__ void stage_x_bf(const unsigned short* __restrict__ g, int r0,
                                           unsigned short* xs, int tid) {
#pragma unroll
  for (int it = 0; it < 8; ++it) {
    int i = it * 256 + tid;
    int row = i >> 5, q = i & 31;
    uint4 v = reinterpret_cast<const uint4*>(g)[(size_t)(r0 + row) * 32 + q];
    *reinterpret_cast<uint4*>(&xs[row * 264 + q * 8]) = v;
  }
}

__device__ __forceinline__ void gemm_frag(const unsigned short* xs,
                                          const unsigned short* __restrict__ Wg,
                                          unsigned short* wl, int tid,
                                          f32x4 accv[4][4]) {
  const int wid = tid >> 6, lhi = (tid & 63) >> 4, llo = tid & 15;
  for (int ks = 0; ks < 8; ++ks) {
    const int k0 = ks * 32;
    __syncthreads();  // protects xs (first iter) and wl reads from prev iter
    {
      const uint4* gp = reinterpret_cast<const uint4*>(Wg + (size_t)tid * 256 + k0);
      uint4 a0 = gp[0], a1 = gp[1], a2 = gp[2], a3 = gp[3];
      uint4* lp = reinterpret_cast<uint4*>(wl + tid * 56);
      lp[0] = a0; lp[1] = a1; lp[2] = a2; lp[3] = a3;
    }
    __syncthreads();
    bf16x8 afr[4], bfr[4];
#pragma unroll
    for (int rt = 0; rt < 4; ++rt)
      afr[rt] = *reinterpret_cast<const bf16x8*>(&xs[(rt * 16 + llo) * 264 + k0 + lhi * 8]);
#pragma unroll
    for (int nt = 0; nt < 4; ++nt)
      bfr[nt] = *reinterpret_cast<const bf16x8*>(&wl[(wid * 64 + nt * 16 + llo) * 56 + lhi * 8]);
#pragma unroll
    for (int rt = 0; rt < 4; ++rt)
#pragma unroll
      for (int nt = 0; nt < 4; ++nt)
        accv[rt][nt] = __builtin_amdgcn_mfma_f32_16x16x32_bf16(afr[rt], bfr[nt], accv[rt][nt], 0, 0, 0);
  }
}

// ---- all 6 relations: acc <- W . acc, in place, bf16 ----
__global__ __launch_bounds__(256) void relT6_kernel(RTab T, const unsigned short* __restrict__ wbf) {
  __shared__ alignas(16) unsigned short xs[64 * 264];
  __shared__ alignas(16) unsigned short wl[256 * 56];
  const int tid = threadIdx.x;
  const int bx = blockIdx.x;
  int r = 0;
#pragma unroll
  for (int k = 1; k < 6; ++k) r += (bx >= T.cum[k]);
  const int r0 = (bx - T.cum[r]) * 64;
  unsigned short* acc = T.acc[r];
  const unsigned short* Wbf = wbf + r * 65536;

  stage_x_bf(acc, r0, xs, tid);

  f32x4 accv[4][4];
#pragma unroll
  for (int a = 0; a < 4; ++a)
#pragma unroll
    for (int b = 0; b < 4; ++b) accv[a][b] = {0.f, 0.f, 0.f, 0.f};

  gemm_frag(xs, Wbf, wl, tid, accv);

  const int wid = tid >> 6, lane = tid & 63, lhi = lane >> 4, llo = lane & 15;
#pragma unroll
  for (int rt = 0; rt < 4; ++rt)
#pragma unroll
    for (int nt = 0; nt < 4; ++nt) {
      int col = wid * 64 + nt * 16 + llo;
#pragma unroll
      for (int rg = 0; rg < 4; ++rg) {
        int row = rt * 16 + lhi * 4 + rg;
        acc[(size_t)(r0 + row) * DIM + col] = f2bf(accv[rt][nt][rg]);
      }
    }
}

// ---- per node type: self-GEMM + relation attention + residual + LN + leaky ----
__global__ __launch_bounds__(256) void fuse_kernel(
    const float* __restrict__ h, const unsigned short* __restrict__ msg1,
    const unsigned short* __restrict__ msg2, const unsigned short* __restrict__ Wbf,
    const float* __restrict__ A1, const float* __restrict__ A2,
    const float* __restrict__ gamma, const float* __restrict__ beta,
    float* __restrict__ out) {
  __shared__ alignas(16) union SM {
    struct { unsigned short x[64 * 264]; unsigned short w[256 * 56]; } g;
    unsigned short s[64 * 260];  // self result, bf16
  } ov;
  __shared__ float sgb[512];
  const int tid = threadIdx.x;
  const int r0 = blockIdx.x * 64;

  stage_x_f32(h, r0, ov.g.x, tid);
  for (int i = tid; i < 512; i += 256) sgb[i] = (i < 256) ? gamma[i] : beta[i - 256];

  f32x4 accv[4][4];
#pragma unroll
  for (int a = 0; a < 4; ++a)
#pragma unroll
    for (int b = 0; b < 4; ++b) accv[a][b] = {0.f, 0.f, 0.f, 0.f};

  gemm_frag(ov.g.x, Wbf, ov.g.w, tid, accv);

  const int wid = tid >> 6, lane = tid & 63, lhi = lane >> 4, llo = lane & 15;
  __syncthreads();  // all MFMA LDS reads done before overlaying ov.s
#pragma unroll
  for (int rt = 0; rt < 4; ++rt)
#pragma unroll
    for (int nt = 0; nt < 4; ++nt) {
      int col = wid * 64 + nt * 16 + llo;
#pragma unroll
      for (int rg = 0; rg < 4; ++rg)
        ov.s[(rt * 16 + lhi * 4 + rg) * 260 + col] = f2bf(accv[rt][nt][rg]);
    }
  __syncthreads();

  // epilogue: wave handles 16 rows; lane owns 4 dims
  const int d0 = lane * 4;
  const float4* A1v = reinterpret_cast<const float4*>(A1);
  const float4* A2v = reinterpret_cast<const float4*>(A2);
  float4 a1f[4], a2f[4];
#pragma unroll
  for (int hh = 0; hh < 4; ++hh) { a1f[hh] = A1v[hh * 64 + lane]; a2f[hh] = A2v[hh * 64 + lane]; }
  const float4 g4 = *reinterpret_cast<const float4*>(&sgb[d0]);
  const float4 b4 = *reinterpret_cast<const float4*>(&sgb[256 + d0]);

  for (int rl = 0; rl < 16; ++rl) {
    int row = wid * 16 + rl;
    size_t gb = (size_t)(r0 + row) * DIM + d0;
    ushort4 m1b = *reinterpret_cast<const ushort4*>(msg1 + gb);
    ushort4 m2b = *reinterpret_cast<const ushort4*>(msg2 + gb);
    float4 m1 = {bf2f(m1b.x), bf2f(m1b.y), bf2f(m1b.z), bf2f(m1b.w)};
    float4 m2 = {bf2f(m2b.x), bf2f(m2b.y), bf2f(m2b.z), bf2f(m2b.w)};
    float4 hvv = *reinterpret_cast<const float4*>(h + gb);
    ushort4 sb = *reinterpret_cast<const ushort4*>(&ov.s[row * 260 + d0]);
    float4 sv = {bf2f(sb.x), bf2f(sb.y), bf2f(sb.z), bf2f(sb.w)};

    float sc[8];
#pragma unroll
    for (int hh = 0; hh < 4; ++hh) {
      sc[hh]     = m1.x * a1f[hh].x + m1.y * a1f[hh].y + m1.z * a1f[hh].z + m1.w * a1f[hh].w;
      sc[4 + hh] = m2.x * a2f[hh].x + m2.y * a2f[hh].y + m2.z * a2f[hh].z + m2.w * a2f[hh].w;
    }
#pragma unroll
    for (int o = 1; o < 64; o <<= 1) {
#pragma unroll
      for (int j = 0; j < 8; ++j) sc[j] += __shfl_xor(sc[j], o);
    }
    // softmax over the 2 relations per head; scale = 1/(sqrt(256)*0.5) = 0.125
    float c1 = 0.f, c2 = 0.f;
#pragma unroll
    for (int hh = 0; hh < 4; ++hh) {
      float s1 = sc[hh] * 0.125f, s2 = sc[4 + hh] * 0.125f;
      float mx = fmaxf(s1, s2);
      float e1 = __expf(s1 - mx), e2 = __expf(s2 - mx);
      float inv = 1.f / (e1 + e2);
      c1 += e1 * inv; c2 += e2 * inv;
    }
    c1 *= 0.25f; c2 *= 0.25f;  // mean over H=4 heads

    float4 u;
    u.x = sv.x + c1 * m1.x + c2 * m2.x + hvv.x;
    u.y = sv.y + c1 * m1.y + c2 * m2.y + hvv.y;
    u.z = sv.z + c1 * m1.z + c2 * m2.z + hvv.z;
    u.w = sv.w + c1 * m1.w + c2 * m2.w + hvv.w;

    float s1v = u.x + u.y + u.z + u.w;
    float s2v = u.x * u.x + u.y * u.y + u.z * u.z + u.w * u.w;
#pragma unroll
    for (int o = 1; o < 64; o <<= 1) { s1v += __shfl_xor(s1v, o); s2v += __shfl_xor(s2v, o); }
    float mu = s1v * (1.f / 256.f);
    float var = s2v * (1.f / 256.f) - mu * mu;
    float rstd = rsqrtf(var + 1e-5f);

    float4 y;
    y.x = (u.x - mu) * rstd * g4.x + b4.x;
    y.y = (u.y - mu) * rstd * g4.y + b4.y;
    y.z = (u.z - mu) * rstd * g4.z + b4.z;
    y.w = (u.w - mu) * rstd * g4.w + b4.w;
    y.x = fmaxf(y.x, 0.01f * y.x);
    y.y = fmaxf(y.y, 0.01f * y.y);
    y.z = fmaxf(y.z, 0.01f * y.z);
    y.w = fmaxf(y.w, 0.01f * y.w);
    *reinterpret_cast<float4*>(out + gb) = y;
  }
}

// ---- workspace layout (bytes) ----
static constexpr size_t AL(size_t x) { return (x + 255) & ~size_t(255); }
static constexpr size_t NROWS = 2 * (NLr + NGr + NDr);                 // 114688
// acc (bf16), relation row-offsets in ushort units
static constexpr size_t ACCe_L2G = 0;
static constexpr size_t ACCe_G2L = ACCe_L2G + (size_t)NGr * DIM;
static constexpr size_t ACCe_G2D = ACCe_G2L + (size_t)NLr * DIM;
static constexpr size_t ACCe_D2G = ACCe_G2D + (size_t)NDr * DIM;
static constexpr size_t ACCe_L2D = ACCe_D2G + (size_t)NGr * DIM;
static constexpr size_t ACCe_D2L = ACCe_L2D + (size_t)NDr * DIM;
static constexpr size_t OFF_ACC  = 0;
static constexpr size_t OFF_HBF  = AL(OFF_ACC + NROWS * DIM * 2);      // h bf16
static constexpr size_t OFF_WBF  = AL(OFF_HBF + (size_t)(NLr + NGr + NDr) * DIM * 2);
static constexpr size_t OFF_HIST = AL(OFF_WBF + 9 * 65536 * 2);
static constexpr size_t OFF_OFFS = AL(OFF_HIST + 6 * HSTRIDE * 4);
static constexpr size_t OFF_CURS = AL(OFF_OFFS + 6 * HSTRIDE * 4);
static constexpr size_t OFF_PART = AL(OFF_CURS + 6 * 32768 * 4);
static constexpr size_t OFF_BOFF = AL(OFF_PART + 48 * 4);
static constexpr size_t OFF_SRCW = AL(OFF_BOFF + 48 * 4);

extern "C" void kernel_launch(void* const* d_in, const int* in_sizes, int n_in,
                              void* d_out, int out_size, void* d_ws, size_t ws_size,
                              hipStream_t stream) {
  char* wsb = (char*)d_ws;
  unsigned short* acc = (unsigned short*)(wsb + OFF_ACC);
  unsigned short* hbf = (unsigned short*)(wsb + OFF_HBF);
  unsigned short* wbf = (unsigned short*)(wsb + OFF_WBF);
  int* hist = (int*)(wsb + OFF_HIST);
  int* offs = (int*)(wsb + OFF_OFFS);
  int* curs = (int*)(wsb + OFF_CURS);
  int* part = (int*)(wsb + OFF_PART);
  int* boff = (int*)(wsb + OFF_BOFF);
  int2* srcw = (int2*)(wsb + OFF_SRCW);
  float* out = (float*)d_out;

  // relation order: l2g, g2l, g2d, d2g, l2d, d2l
  const int base[6] = {3, 8, 13, 18, 23, 28};
  const int hidx[6] = {0, 1, 1, 2, 0, 2};
  const int ndst[6] = {NGr, NLr, NDr, NGr, NDr, NLr};
  const size_t accOff[6] = {ACCe_L2G, ACCe_G2L, ACCe_G2D, ACCe_D2G, ACCe_L2D, ACCe_D2L};
  const size_t hbOff[3] = {0, (size_t)NLr * DIM, (size_t)(NLr + NGr) * DIM};

  // weights -> bf16: slots 0..5 = W_rel, 6..8 = Wself_{l,g,d}
  WPtrs wp;
  wp.p[0] = (const float*)d_in[6];  wp.p[1] = (const float*)d_in[11];
  wp.p[2] = (const float*)d_in[16]; wp.p[3] = (const float*)d_in[21];
  wp.p[4] = (const float*)d_in[26]; wp.p[5] = (const float*)d_in[31];
  wp.p[6] = (const float*)d_in[33]; wp.p[7] = (const float*)d_in[36];
  wp.p[8] = (const float*)d_in[39];
  conv_w_kernel<<<dim3(256, 9), 256, 0, stream>>>(wp, wbf);

  // h -> bf16
  H3 X;
  X.h[0] = (const float*)d_in[0]; X.h[1] = (const float*)d_in[1]; X.h[2] = (const float*)d_in[2];
  X.cnt4[0] = NLr * 64; X.cnt4[1] = NGr * 64; X.cnt4[2] = NDr * 64;
  X.obase[0] = 0; X.obase[1] = NLr * 64; X.obase[2] = (NLr + NGr) * 64;
  h2bf_kernel<<<dim3(2048, 3), 256, 0, stream>>>(X, hbf);

  // CSR build
  (void)hipMemsetAsync(hist, 0, 6 * HSTRIDE * 4, stream);
  RelIdx R; NTab N; ETab Eb;
  for (int r = 0; r < 6; ++r) {
    R.dst[r] = (const int*)d_in[base[r] + 1];
    N.n[r] = ndst[r];
    Eb.src[r] = (const int*)d_in[base[r]];
    Eb.dst[r] = (const int*)d_in[base[r] + 1];
    Eb.w[r]  = (const float*)d_in[base[r] + 2];
  }
  hist6_kernel<<<dim3(NE / 256, 6), 256, 0, stream>>>(R, hist);
  scanA_kernel<<<dim3(8, 6), 256, 0, stream>>>(hist, part, N);
  scanTop_kernel<<<1, 64, 0, stream>>>(part, boff);
  scanC_kernel<<<dim3(8, 6), 256, 0, stream>>>(hist, boff, offs, curs, N);
  scatter6_kernel<<<dim3(NE / 256, 6), 256, 0, stream>>>(Eb, offs, curs, srcw);

  // gather (merged, bf16 in/out)
  GTab G;
  int cumG = 0;
  for (int r = 0; r < 6; ++r) {
    G.hb[r] = hbf + hbOff[hidx[r]];
    G.acc[r] = acc + accOff[r];
    G.sw[r] = srcw + (size_t)r * NE;
    G.of[r] = offs + r * HSTRIDE;
    G.cum[r] = cumG;
    cumG += ndst[r] / 4;
  }
  G.cum[6] = cumG;
  gather6_kernel<<<cumG, 256, 0, stream>>>(G);

  // relation transforms (merged, in-place bf16)
  RTab T;
  int cumR = 0;
  for (int r = 0; r < 6; ++r) {
    T.acc[r] = acc + accOff[r];
    T.cum[r] = cumR;
    cumR += ndst[r] / 64;
  }
  T.cum[6] = cumR;
  relT6_kernel<<<cumR, 256, 0, stream>>>(T, wbf);

  // type l: msgs [g2l, d2l]
  fuse_kernel<<<NLr / 64, 256, 0, stream>>>(
      (const float*)d_in[0], acc + ACCe_G2L, acc + ACCe_D2L, wbf + 6 * 65536,
      (const float*)d_in[12], (const float*)d_in[32],
      (const float*)d_in[34], (const float*)d_in[35], out);
  // type g: msgs [l2g, d2g]
  fuse_kernel<<<NGr / 64, 256, 0, stream>>>(
      (const float*)d_in[1], acc + ACCe_L2G, acc + ACCe_D2G, wbf + 7 * 65536,
      (const float*)d_in[7], (const float*)d_in[22],
      (const float*)d_in[37], (const float*)d_in[38], out + (size_t)NLr * DIM);
  // type d: msgs [g2d, l2d]
  fuse_kernel<<<NDr / 64, 256, 0, stream>>>(
      (const float*)d_in[2], acc + ACCe_G2D, acc + ACCe_L2D, wbf + 8 * 65536,
      (const float*)d_in[17], (const float*)d_in[27],
      (const float*)d_in[40], (const float*)d_in[41], out + (size_t)(NLr + NGr) * DIM);
}

// Round 6
// 434.859 us; speedup vs baseline: 12.7129x; 1.0359x over previous
//
#include <hip/hip_runtime.h>

#define DIM 256
#define NLr 16384
#define NGr 32768
#define NDr 8192
#define NE  262144
#define HSTRIDE 32772  // hist/offs per-relation stride (16B-aligned)

typedef short bf16x8 __attribute__((ext_vector_type(8)));
typedef float f32x4 __attribute__((ext_vector_type(4)));

__device__ __forceinline__ unsigned short f2bf(float f) {
  unsigned int u = __builtin_bit_cast(unsigned int, f);
  u += 0x7fffu + ((u >> 16) & 1u);
  return (unsigned short)(u >> 16);
}
__device__ __forceinline__ float bf2f(unsigned short b) {
  return __builtin_bit_cast(float, ((unsigned int)b) << 16);
}
__device__ __forceinline__ float bflo(unsigned int u) {
  return __builtin_bit_cast(float, u << 16);
}
__device__ __forceinline__ float bfhi(unsigned int u) {
  return __builtin_bit_cast(float, u & 0xffff0000u);
}

struct WPtrs { const float* p[9]; };
struct H3 { const float* h[3]; int cnt4[3]; int obase[3]; };
struct NTab { int n[6]; };
struct RelIdx { const int* dst[6]; };
struct ETab { const int* src[6]; const int* dst[6]; const float* w[6]; };
struct GTab { const unsigned short* hb[6]; unsigned short* acc[6];
              const int2* sw[6]; const int* of[6]; int cum[7]; };
struct RTab { unsigned short* acc[6]; int cum[7]; };

// ---- convert 9 weight matrices (f32 -> bf16), 65536 elems each ----
__global__ __launch_bounds__(256) void conv_w_kernel(WPtrs wp, unsigned short* __restrict__ dst) {
  int m = blockIdx.y;
  int i = blockIdx.x * 256 + threadIdx.x;
  dst[m * 65536 + i] = f2bf(wp.p[m][i]);
}

// ---- convert h_l,h_g,h_d to bf16 ----
__global__ __launch_bounds__(256) void h2bf_kernel(H3 X, unsigned short* __restrict__ hbf) {
  int t = blockIdx.y;
  const float4* sv = reinterpret_cast<const float4*>(X.h[t]);
  uint2* ob = reinterpret_cast<uint2*>(hbf) + X.obase[t];
  unsigned cnt = X.cnt4[t];
  for (unsigned i = blockIdx.x * 256 + threadIdx.x; i < cnt; i += gridDim.x * 256) {
    float4 v = sv[i];
    uint2 o;
    o.x = (unsigned)f2bf(v.x) | ((unsigned)f2bf(v.y) << 16);
    o.y = (unsigned)f2bf(v.z) | ((unsigned)f2bf(v.w) << 16);
    ob[i] = o;
  }
}

// ---- CSR build: histogram over dst for all 6 relations ----
__global__ __launch_bounds__(256) void hist6_kernel(RelIdx R, int* __restrict__ hist) {
  int r = blockIdx.y;
  int e = blockIdx.x * 256 + threadIdx.x;
  atomicAdd(&hist[r * HSTRIDE + R.dst[r][e]], 1);
}

// ---- scan stage A: per-block partial sums (4096 bins / block) ----
__global__ __launch_bounds__(256) void scanA_kernel(const int* __restrict__ hist,
                                                    int* __restrict__ partials, NTab N) {
  int r = blockIdx.y, b = blockIdx.x;
  int n = N.n[r], base = b * 4096;
  int s = 0;
  if (base < n) {
    const int4* h4 = reinterpret_cast<const int4*>(hist + r * HSTRIDE + base);
#pragma unroll
    for (int k = 0; k < 4; ++k) {
      int4 v = h4[threadIdx.x * 4 + k];
      s += v.x + v.y + v.z + v.w;
    }
  }
#pragma unroll
  for (int o = 1; o < 64; o <<= 1) s += __shfl_xor(s, o);
  __shared__ int wsum[4];
  if ((threadIdx.x & 63) == 0) wsum[threadIdx.x >> 6] = s;
  __syncthreads();
  if (threadIdx.x == 0) partials[r * 8 + b] = wsum[0] + wsum[1] + wsum[2] + wsum[3];
}

// ---- scan stage B: tiny per-relation exclusive scan of 8 partials ----
__global__ void scanTop_kernel(const int* __restrict__ partials, int* __restrict__ boff) {
  int r = threadIdx.x;
  if (r < 6) {
    int off = 0;
    for (int b = 0; b < 8; ++b) { boff[r * 8 + b] = off; off += partials[r * 8 + b]; }
  }
}

// ---- scan stage C: block-local scan + write offs + zero cursor + offs[n]=NE ----
// reproduces round-3 scan6 outputs exactly (offs = exclusive prefix, cursor = 0)
__global__ __launch_bounds__(256) void scanC_kernel(const int* __restrict__ hist,
                                                    const int* __restrict__ boff,
                                                    int* __restrict__ offs,
                                                    int* __restrict__ cursor, NTab N) {
  int r = blockIdx.y, b = blockIdx.x;
  int n = N.n[r], base = b * 4096;
  if (b == 0 && threadIdx.x == 0) offs[r * HSTRIDE + n] = NE;
  if (base >= n) return;
  const int tid = threadIdx.x;
  int vals[16];
  int s = 0;
  const int4* h4 = reinterpret_cast<const int4*>(hist + r * HSTRIDE + base);
#pragma unroll
  for (int k = 0; k < 4; ++k) {
    int4 v = h4[tid * 4 + k];
    vals[4 * k] = v.x; vals[4 * k + 1] = v.y; vals[4 * k + 2] = v.z; vals[4 * k + 3] = v.w;
    s += v.x + v.y + v.z + v.w;
  }
  __shared__ int part[256];
  part[tid] = s;
  __syncthreads();
  for (int off = 1; off < 256; off <<= 1) {
    int v = (tid >= off) ? part[tid - off] : 0;
    __syncthreads();
    part[tid] += v;
    __syncthreads();
  }
  int run = part[tid] - s + boff[r * 8 + b];
  int gbase = base + tid * 16;
#pragma unroll
  for (int j = 0; j < 16; ++j) {
    offs[r * HSTRIDE + gbase + j] = run;
    run += vals[j];
    cursor[r * 32768 + gbase + j] = 0;
  }
}

// ---- CSR build: bucket-scatter packed (src, w), explicit cursor (round-3) ----
__global__ __launch_bounds__(256) void scatter6_kernel(ETab E, const int* __restrict__ offs,
                                                       int* __restrict__ cursor,
                                                       int2* __restrict__ srcw) {
  int r = blockIdx.y;
  int e = blockIdx.x * 256 + threadIdx.x;
  int d = E.dst[r][e];
  int pos = offs[r * HSTRIDE + d] + atomicAdd(&cursor[r * 32768 + d], 1);
  srcw[(size_t)r * NE + pos] = make_int2(E.src[r][e], __builtin_bit_cast(int, E.w[r][e]));
}

// ---- gather: acc[node] = (sum w_e * hb[src_e]) / deg, one wave per node ----
// round-3 bucket semantics [offs[node], offs[node+1]), unroll-4 body
__global__ __launch_bounds__(256) void gather6_kernel(GTab T) {
  const int bx = blockIdx.x;
  int r = 0;
#pragma unroll
  for (int k = 1; k < 6; ++k) r += (bx >= T.cum[k]);
  const int node = (bx - T.cum[r]) * 4 + (threadIdx.x >> 6);
  const int lane = threadIdx.x & 63;
  const int* of = T.of[r];
  const int beg = of[node], end = of[node + 1];
  const uint2* __restrict__ hv = reinterpret_cast<const uint2*>(T.hb[r]);
  const int2* __restrict__ sw = T.sw[r];
  float4 a = {0.f, 0.f, 0.f, 0.f};
  float degw = 0.f;
  int j = beg;
  for (; j + 3 < end; j += 4) {
    int2 p0 = sw[j], p1 = sw[j + 1], p2 = sw[j + 2], p3 = sw[j + 3];
    float w0 = __builtin_bit_cast(float, p0.y);
    float w1 = __builtin_bit_cast(float, p1.y);
    float w2 = __builtin_bit_cast(float, p2.y);
    float w3 = __builtin_bit_cast(float, p3.y);
    uint2 x0 = hv[(size_t)p0.x * 64 + lane];
    uint2 x1 = hv[(size_t)p1.x * 64 + lane];
    uint2 x2 = hv[(size_t)p2.x * 64 + lane];
    uint2 x3 = hv[(size_t)p3.x * 64 + lane];
    degw += (w0 + w1) + (w2 + w3);
    a.x += w0 * bflo(x0.x) + w1 * bflo(x1.x) + w2 * bflo(x2.x) + w3 * bflo(x3.x);
    a.y += w0 * bfhi(x0.x) + w1 * bfhi(x1.x) + w2 * bfhi(x2.x) + w3 * bfhi(x3.x);
    a.z += w0 * bflo(x0.y) + w1 * bflo(x1.y) + w2 * bflo(x2.y) + w3 * bflo(x3.y);
    a.w += w0 * bfhi(x0.y) + w1 * bfhi(x1.y) + w2 * bfhi(x2.y) + w3 * bfhi(x3.y);
  }
  for (; j < end; ++j) {
    int2 p0 = sw[j];
    float w0 = __builtin_bit_cast(float, p0.y);
    uint2 x0 = hv[(size_t)p0.x * 64 + lane];
    degw += w0;
    a.x += w0 * bflo(x0.x); a.y += w0 * bfhi(x0.x);
    a.z += w0 * bflo(x0.y); a.w += w0 * bfhi(x0.y);
  }
  float inv = (degw == 0.f) ? 1.f : 1.f / degw;
  uint2 o;
  o.x = (unsigned)f2bf(a.x * inv) | ((unsigned)f2bf(a.y * inv) << 16);
  o.y = (unsigned)f2bf(a.z * inv) | ((unsigned)f2bf(a.w * inv) << 16);
  reinterpret_cast<uint2*>(T.acc[r])[(size_t)node * 64 + lane] = o;
}

// ---- shared GEMM pieces: 64 rows x (256x256) bf16 MFMA (round-3 proven) ----
__device__ __forceinline__ void stage_x_f32(const float* __restrict__ g, int r0,
                                            unsigned short* xs, int tid) {
#pragma unroll
  for (int it = 0; it < 16; ++it) {
    int i = it * 256 + tid;
    int row = i >> 6, q = i & 63;
    float4 v = reinterpret_cast<const float4*>(g)[(size_t)(r0 + row) * 64 + q];
    ushort4 b;
    b.x = f2bf(v.x); b.y = f2bf(v.y); b.z = f2bf(v.z); b.w = f2bf(v.w);
    *reinterpret_cast<ushort4*>(&xs[row * 264 + q * 4]) = b;
  }
}

__device__ __forceinline__ void stage_x_bf(const unsigned short* __restrict__ g, int r0,
                                           unsigned short* xs, int tid) {
#pragma unroll
  for (int it = 0; it < 8; ++it) {
    int i = it * 256 + tid;
    int row = i >> 5, q = i & 31;
    uint4 v = reinterpret_cast<const uint4*>(g)[(size_t)(r0 + row) * 32 + q];
    *reinterpret_cast<uint4*>(&xs[row * 264 + q * 8]) = v;
  }
}

__device__ __forceinline__ void gemm_frag(const unsigned short* xs,
                                          const unsigned short* __restrict__ Wg,
                                          unsigned short* wl, int tid,
                                          f32x4 accv[4][4]) {
  const int wid = tid >> 6, lhi = (tid & 63) >> 4, llo = tid & 15;
  for (int ks = 0; ks < 8; ++ks) {
    const int k0 = ks * 32;
    __syncthreads();  // protects xs (first iter) and wl reads from prev iter
    {
      const uint4* gp = reinterpret_cast<const uint4*>(Wg + (size_t)tid * 256 + k0);
      uint4 a0 = gp[0], a1 = gp[1], a2 = gp[2], a3 = gp[3];
      uint4* lp = reinterpret_cast<uint4*>(wl + tid * 56);
      lp[0] = a0; lp[1] = a1; lp[2] = a2; lp[3] = a3;
    }
    __syncthreads();
    bf16x8 afr[4], bfr[4];
#pragma unroll
    for (int rt = 0; rt < 4; ++rt)
      afr[rt] = *reinterpret_cast<const bf16x8*>(&xs[(rt * 16 + llo) * 264 + k0 + lhi * 8]);
#pragma unroll
    for (int nt = 0; nt < 4; ++nt)
      bfr[nt] = *reinterpret_cast<const bf16x8*>(&wl[(wid * 64 + nt * 16 + llo) * 56 + lhi * 8]);
#pragma unroll
    for (int rt = 0; rt < 4; ++rt)
#pragma unroll
      for (int nt = 0; nt < 4; ++nt)
        accv[rt][nt] = __builtin_amdgcn_mfma_f32_16x16x32_bf16(afr[rt], bfr[nt], accv[rt][nt], 0, 0, 0);
  }
}

// ---- all 6 relations: acc <- acc @ W^T, in place, bf16 (round-3 proven) ----
__global__ __launch_bounds__(256) void relT6_kernel(RTab T, const unsigned short* __restrict__ wbf) {
  __shared__ alignas(16) unsigned short xs[64 * 264];
  __shared__ alignas(16) unsigned short wl[256 * 56];
  const int tid = threadIdx.x;
  const int bx = blockIdx.x;
  int r = 0;
#pragma unroll
  for (int k = 1; k < 6; ++k) r += (bx >= T.cum[k]);
  const int r0 = (bx - T.cum[r]) * 64;
  unsigned short* acc = T.acc[r];
  const unsigned short* Wbf = wbf + r * 65536;

  stage_x_bf(acc, r0, xs, tid);

  f32x4 accv[4][4];
#pragma unroll
  for (int a = 0; a < 4; ++a)
#pragma unroll
    for (int b = 0; b < 4; ++b) accv[a][b] = {0.f, 0.f, 0.f, 0.f};

  gemm_frag(xs, Wbf, wl, tid, accv);

  const int wid = tid >> 6, lane = tid & 63, lhi = lane >> 4, llo = lane & 15;
#pragma unroll
  for (int rt = 0; rt < 4; ++rt)
#pragma unroll
    for (int nt = 0; nt < 4; ++nt) {
      int col = wid * 64 + nt * 16 + llo;
#pragma unroll
      for (int rg = 0; rg < 4; ++rg) {
        int row = rt * 16 + lhi * 4 + rg;
        acc[(size_t)(r0 + row) * DIM + col] = f2bf(accv[rt][nt][rg]);
      }
    }
}

// ---- per node type: self-GEMM + relation attention + residual + LN + leaky ----
__global__ __launch_bounds__(256) void fuse_kernel(
    const float* __restrict__ h, const unsigned short* __restrict__ msg1,
    const unsigned short* __restrict__ msg2, const unsigned short* __restrict__ Wbf,
    const float* __restrict__ A1, const float* __restrict__ A2,
    const float* __restrict__ gamma, const float* __restrict__ beta,
    float* __restrict__ out) {
  __shared__ alignas(16) union SM {
    struct { unsigned short x[64 * 264]; unsigned short w[256 * 56]; } g;
    unsigned short s[64 * 260];  // self result, bf16
  } ov;
  __shared__ float sgb[512];
  const int tid = threadIdx.x;
  const int r0 = blockIdx.x * 64;

  stage_x_f32(h, r0, ov.g.x, tid);
  for (int i = tid; i < 512; i += 256) sgb[i] = (i < 256) ? gamma[i] : beta[i - 256];

  f32x4 accv[4][4];
#pragma unroll
  for (int a = 0; a < 4; ++a)
#pragma unroll
    for (int b = 0; b < 4; ++b) accv[a][b] = {0.f, 0.f, 0.f, 0.f};

  gemm_frag(ov.g.x, Wbf, ov.g.w, tid, accv);

  const int wid = tid >> 6, lane = tid & 63, lhi = lane >> 4, llo = lane & 15;
  __syncthreads();  // all MFMA LDS reads done before overlaying ov.s
#pragma unroll
  for (int rt = 0; rt < 4; ++rt)
#pragma unroll
    for (int nt = 0; nt < 4; ++nt) {
      int col = wid * 64 + nt * 16 + llo;
#pragma unroll
      for (int rg = 0; rg < 4; ++rg)
        ov.s[(rt * 16 + lhi * 4 + rg) * 260 + col] = f2bf(accv[rt][nt][rg]);
    }
  __syncthreads();

  // epilogue: wave handles 16 rows; lane owns 4 dims
  const int d0 = lane * 4;
  const float4* A1v = reinterpret_cast<const float4*>(A1);
  const float4* A2v = reinterpret_cast<const float4*>(A2);
  float4 a1f[4], a2f[4];
#pragma unroll
  for (int hh = 0; hh < 4; ++hh) { a1f[hh] = A1v[hh * 64 + lane]; a2f[hh] = A2v[hh * 64 + lane]; }
  const float4 g4 = *reinterpret_cast<const float4*>(&sgb[d0]);
  const float4 b4 = *reinterpret_cast<const float4*>(&sgb[256 + d0]);

  for (int rl = 0; rl < 16; ++rl) {
    int row = wid * 16 + rl;
    size_t gb = (size_t)(r0 + row) * DIM + d0;
    ushort4 m1b = *reinterpret_cast<const ushort4*>(msg1 + gb);
    ushort4 m2b = *reinterpret_cast<const ushort4*>(msg2 + gb);
    float4 m1 = {bf2f(m1b.x), bf2f(m1b.y), bf2f(m1b.z), bf2f(m1b.w)};
    float4 m2 = {bf2f(m2b.x), bf2f(m2b.y), bf2f(m2b.z), bf2f(m2b.w)};
    float4 hvv = *reinterpret_cast<const float4*>(h + gb);
    ushort4 sb = *reinterpret_cast<const ushort4*>(&ov.s[row * 260 + d0]);
    float4 sv = {bf2f(sb.x), bf2f(sb.y), bf2f(sb.z), bf2f(sb.w)};

    float sc[8];
#pragma unroll
    for (int hh = 0; hh < 4; ++hh) {
      sc[hh]     = m1.x * a1f[hh].x + m1.y * a1f[hh].y + m1.z * a1f[hh].z + m1.w * a1f[hh].w;
      sc[4 + hh] = m2.x * a2f[hh].x + m2.y * a2f[hh].y + m2.z * a2f[hh].z + m2.w * a2f[hh].w;
    }
#pragma unroll
    for (int o = 1; o < 64; o <<= 1) {
#pragma unroll
      for (int j = 0; j < 8; ++j) sc[j] += __shfl_xor(sc[j], o);
    }
    // softmax over the 2 relations per head; scale = 1/(sqrt(256)*0.5) = 0.125
    float c1 = 0.f, c2 = 0.f;
#pragma unroll
    for (int hh = 0; hh < 4; ++hh) {
      float s1 = sc[hh] * 0.125f, s2 = sc[4 + hh] * 0.125f;
      float mx = fmaxf(s1, s2);
      float e1 = __expf(s1 - mx), e2 = __expf(s2 - mx);
      float inv = 1.f / (e1 + e2);
      c1 += e1 * inv; c2 += e2 * inv;
    }
    c1 *= 0.25f; c2 *= 0.25f;  // mean over H=4 heads

    float4 u;
    u.x = sv.x + c1 * m1.x + c2 * m2.x + hvv.x;
    u.y = sv.y + c1 * m1.y + c2 * m2.y + hvv.y;
    u.z = sv.z + c1 * m1.z + c2 * m2.z + hvv.z;
    u.w = sv.w + c1 * m1.w + c2 * m2.w + hvv.w;

    float s1v = u.x + u.y + u.z + u.w;
    float s2v = u.x * u.x + u.y * u.y + u.z * u.z + u.w * u.w;
#pragma unroll
    for (int o = 1; o < 64; o <<= 1) { s1v += __shfl_xor(s1v, o); s2v += __shfl_xor(s2v, o); }
    float mu = s1v * (1.f / 256.f);
    float var = s2v * (1.f / 256.f) - mu * mu;
    float rstd = rsqrtf(var + 1e-5f);

    float4 y;
    y.x = (u.x - mu) * rstd * g4.x + b4.x;
    y.y = (u.y - mu) * rstd * g4.y + b4.y;
    y.z = (u.z - mu) * rstd * g4.z + b4.z;
    y.w = (u.w - mu) * rstd * g4.w + b4.w;
    y.x = fmaxf(y.x, 0.01f * y.x);
    y.y = fmaxf(y.y, 0.01f * y.y);
    y.z = fmaxf(y.z, 0.01f * y.z);
    y.w = fmaxf(y.w, 0.01f * y.w);
    *reinterpret_cast<float4*>(out + gb) = y;
  }
}

// ---- workspace layout (bytes); ~75 MB, round-3 proven footprint ----
static constexpr size_t AL(size_t x) { return (x + 255) & ~size_t(255); }
// acc (bf16), relation row-offsets in ushort units (dst-sized)
static constexpr size_t ACCe_L2G = 0;
static constexpr size_t ACCe_G2L = ACCe_L2G + (size_t)NGr * DIM;
static constexpr size_t ACCe_G2D = ACCe_G2L + (size_t)NLr * DIM;
static constexpr size_t ACCe_D2G = ACCe_G2D + (size_t)NDr * DIM;
static constexpr size_t ACCe_L2D = ACCe_D2G + (size_t)NGr * DIM;
static constexpr size_t ACCe_D2L = ACCe_L2D + (size_t)NDr * DIM;
static constexpr size_t ACC_TOT  = ACCe_D2L + (size_t)NLr * DIM;
static constexpr size_t OFF_ACC  = 0;
static constexpr size_t OFF_HBF  = AL(OFF_ACC + ACC_TOT * 2);
static constexpr size_t OFF_WBF  = AL(OFF_HBF + (size_t)(NLr + NGr + NDr) * DIM * 2);
static constexpr size_t OFF_HIST = AL(OFF_WBF + 9 * 65536 * 2);
static constexpr size_t OFF_OFFS = AL(OFF_HIST + 6 * HSTRIDE * 4);
static constexpr size_t OFF_CURS = AL(OFF_OFFS + 6 * HSTRIDE * 4);
static constexpr size_t OFF_PART = AL(OFF_CURS + 6 * 32768 * 4);
static constexpr size_t OFF_BOFF = AL(OFF_PART + 48 * 4);
static constexpr size_t OFF_SRCW = AL(OFF_BOFF + 48 * 4);

extern "C" void kernel_launch(void* const* d_in, const int* in_sizes, int n_in,
                              void* d_out, int out_size, void* d_ws, size_t ws_size,
                              hipStream_t stream) {
  char* wsb = (char*)d_ws;
  unsigned short* acc = (unsigned short*)(wsb + OFF_ACC);
  unsigned short* hbf = (unsigned short*)(wsb + OFF_HBF);
  unsigned short* wbf = (unsigned short*)(wsb + OFF_WBF);
  int* hist = (int*)(wsb + OFF_HIST);
  int* offs = (int*)(wsb + OFF_OFFS);
  int* curs = (int*)(wsb + OFF_CURS);
  int* part = (int*)(wsb + OFF_PART);
  int* boff = (int*)(wsb + OFF_BOFF);
  int2* srcw = (int2*)(wsb + OFF_SRCW);
  float* out = (float*)d_out;

  // relation order: l2g, g2l, g2d, d2g, l2d, d2l
  const int base[6] = {3, 8, 13, 18, 23, 28};
  const int hidx[6] = {0, 1, 1, 2, 0, 2};              // SOURCE type per relation
  const int ndst[6] = {NGr, NLr, NDr, NGr, NDr, NLr};
  const size_t accOff[6] = {ACCe_L2G, ACCe_G2L, ACCe_G2D, ACCe_D2G, ACCe_L2D, ACCe_D2L};
  const size_t hbOff[3] = {0, (size_t)NLr * DIM, (size_t)(NLr + NGr) * DIM};

  // weights -> bf16: slots 0..5 = W_rel, 6..8 = Wself_{l,g,d}
  WPtrs wp;
  wp.p[0] = (const float*)d_in[6];  wp.p[1] = (const float*)d_in[11];
  wp.p[2] = (const float*)d_in[16]; wp.p[3] = (const float*)d_in[21];
  wp.p[4] = (const float*)d_in[26]; wp.p[5] = (const float*)d_in[31];
  wp.p[6] = (const float*)d_in[33]; wp.p[7] = (const float*)d_in[36];
  wp.p[8] = (const float*)d_in[39];
  conv_w_kernel<<<dim3(256, 9), 256, 0, stream>>>(wp, wbf);

  // h -> bf16
  H3 X;
  X.h[0] = (const float*)d_in[0]; X.h[1] = (const float*)d_in[1]; X.h[2] = (const float*)d_in[2];
  X.cnt4[0] = NLr * 64; X.cnt4[1] = NGr * 64; X.cnt4[2] = NDr * 64;
  X.obase[0] = 0; X.obase[1] = NLr * 64; X.obase[2] = (NLr + NGr) * 64;
  h2bf_kernel<<<dim3(2048, 3), 256, 0, stream>>>(X, hbf);

  // CSR build (fast multi-block scan)
  (void)hipMemsetAsync(hist, 0, 6 * HSTRIDE * 4, stream);
  RelIdx R; NTab N; ETab Eb;
  for (int r = 0; r < 6; ++r) {
    R.dst[r] = (const int*)d_in[base[r] + 1];
    N.n[r] = ndst[r];
    Eb.src[r] = (const int*)d_in[base[r]];
    Eb.dst[r] = (const int*)d_in[base[r] + 1];
    Eb.w[r]  = (const float*)d_in[base[r] + 2];
  }
  hist6_kernel<<<dim3(NE / 256, 6), 256, 0, stream>>>(R, hist);
  scanA_kernel<<<dim3(8, 6), 256, 0, stream>>>(hist, part, N);
  scanTop_kernel<<<1, 64, 0, stream>>>(part, boff);
  scanC_kernel<<<dim3(8, 6), 256, 0, stream>>>(hist, boff, offs, curs, N);
  scatter6_kernel<<<dim3(NE / 256, 6), 256, 0, stream>>>(Eb, offs, curs, srcw);

  // gather (merged, bf16 in/out, unroll-4)
  GTab G;
  int cumG = 0;
  for (int r = 0; r < 6; ++r) {
    G.hb[r] = hbf + hbOff[hidx[r]];
    G.acc[r] = acc + accOff[r];
    G.sw[r] = srcw + (size_t)r * NE;
    G.of[r] = offs + r * HSTRIDE;
    G.cum[r] = cumG;
    cumG += ndst[r] / 4;
  }
  G.cum[6] = cumG;
  gather6_kernel<<<cumG, 256, 0, stream>>>(G);

  // relation transforms (merged, in-place bf16)
  RTab T;
  int cumR = 0;
  for (int r = 0; r < 6; ++r) {
    T.acc[r] = acc + accOff[r];
    T.cum[r] = cumR;
    cumR += ndst[r] / 64;
  }
  T.cum[6] = cumR;
  relT6_kernel<<<cumR, 256, 0, stream>>>(T, wbf);

  // type l: msgs [g2l, d2l]
  fuse_kernel<<<NLr / 64, 256, 0, stream>>>(
      (const float*)d_in[0], acc + ACCe_G2L, acc + ACCe_D2L, wbf + 6 * 65536,
      (const float*)d_in[12], (const float*)d_in[32],
      (const float*)d_in[34], (const float*)d_in[35], out);
  // type g: msgs [l2g, d2g]
  fuse_kernel<<<NGr / 64, 256, 0, stream>>>(
      (const float*)d_in[1], acc + ACCe_L2G, acc + ACCe_D2G, wbf + 7 * 65536,
      (const float*)d_in[7], (const float*)d_in[22],
      (const float*)d_in[37], (const float*)d_in[38], out + (size_t)NLr * DIM);
  // type d: msgs [g2d, l2d]
  fuse_kernel<<<NDr / 64, 256, 0, stream>>>(
      (const float*)d_in[2], acc + ACCe_G2D, acc + ACCe_L2D, wbf + 8 * 65536,
      (const float*)d_in[17], (const float*)d_in[27],
      (const float*)d_in[40], (const float*)d_in[41], out + (size_t)(NLr + NGr) * DIM);
}